// Round 6
// baseline (283.100 us; speedup 1.0000x reference)
//
#include <hip/hip_runtime.h>
#include <math.h>

// B=16 rows, D=2^21 fp32/row. loss = mean_i sqrt(sum_j (out-lab)^2).
// R1-R5: delivered read BW pinned at 2.6-2.7 TB/s, invariant to atomics,
// MLP (2->8, verified via VGPR 64 + sched_barrier), occupancy, grid, VGPR.
// FETCH = exactly one array (label L3-hot, output HBM). Demand knobs dead.
// R6 probe: clock-droop theory. Memory-only kernels (VALUBusy 3%) may get
// SCLK dropped by power mgmt; at ~1.05 GHz, 10 B/cyc/CU streaming = exactly
// 2.7 TB/s. Interleave a hidden dependent-FMA ballast (4096/thread) to raise
// VALUBusy ~50% and hold clocks. Numerically inert.

constexpr int B = 16;
constexpr int D = 2097152;                       // 2^21
constexpr int THREADS = 256;
constexpr int VEC_PER_THREAD = 8;                // float4s per thread
constexpr int FLOATS_PER_BLOCK = THREADS * VEC_PER_THREAD * 4;   // 8192
constexpr int BLOCKS_PER_ROW = D / FLOATS_PER_BLOCK;             // 256
constexpr int GRID = B * BLOCKS_PER_ROW;                         // 4096
constexpr int BALLAST_PER_ITER = 512;            // dependent FMAs per outer iter

__global__ __launch_bounds__(THREADS)
void sqdiff_partial_kernel(const float4* __restrict__ out,
                           const float4* __restrict__ lab,
                           float* __restrict__ partials) {
    const int row   = blockIdx.x / BLOCKS_PER_ROW;
    const int chunk = blockIdx.x % BLOCKS_PER_ROW;
    const size_t base = (size_t)row * (D / 4)
                      + (size_t)chunk * (THREADS * VEC_PER_THREAD);

    float acc = 0.0f;
    // ballast seed: runtime value, slowly-growing positive, provably < 1e-4
    float u = (float)threadIdx.x * 1e-8f + 1e-9f;

#pragma unroll
    for (int i = 0; i < VEC_PER_THREAD; ++i) {
        const size_t idx = base + (size_t)threadIdx.x + (size_t)i * THREADS;
        const float4 o = out[idx];
        const float4 l = lab[idx];

        // VALU ballast: dependent chain, overlaps this iteration's loads.
        // 512 x 8 iters = 4096 FMAs/thread; hidden under memory waits.
        for (int j = 0; j < BALLAST_PER_ITER / 64; ++j) {
#pragma unroll
            for (int k = 0; k < 64; ++k)
                u = fmaf(u, 1.00000012f, 1e-9f);
        }

        const float dx = o.x - l.x;
        const float dy = o.y - l.y;
        const float dz = o.z - l.z;
        const float dw = o.w - l.w;
        acc = fmaf(dx, dx, acc);
        acc = fmaf(dy, dy, acc);
        acc = fmaf(dz, dz, acc);
        acc = fmaf(dw, dw, acc);
    }

    // fold ballast in as exactly +0.0f (u stays < 1e-4; branch never taken,
    // but compiler cannot prove it -> no DCE of the chain)
    acc += (u > 1e30f) ? u : 0.0f;

    // wave-64 tree reduce
#pragma unroll
    for (int off = 32; off > 0; off >>= 1)
        acc += __shfl_down(acc, off, 64);

    __shared__ float smem[THREADS / 64];
    const int lane = threadIdx.x & 63;
    const int wave = threadIdx.x >> 6;
    if (lane == 0) smem[wave] = acc;
    __syncthreads();

    if (threadIdx.x == 0)
        partials[blockIdx.x] = smem[0] + smem[1] + smem[2] + smem[3];
}

// One block, 1024 threads = 16 waves. Wave w reduces row w's 256 partials.
__global__ __launch_bounds__(1024)
void finalize_kernel(const float* __restrict__ partials,
                     float* __restrict__ loss) {
    const int wave = threadIdx.x >> 6;   // row
    const int lane = threadIdx.x & 63;

    float s = 0.0f;
#pragma unroll
    for (int k = 0; k < BLOCKS_PER_ROW / 64; ++k)
        s += partials[wave * BLOCKS_PER_ROW + k * 64 + lane];

#pragma unroll
    for (int off = 32; off > 0; off >>= 1)
        s += __shfl_down(s, off, 64);

    __shared__ float row_dist[B];
    if (lane == 0) row_dist[wave] = sqrtf(s);
    __syncthreads();

    if (wave == 0) {
        float v = (lane < B) ? row_dist[lane] : 0.0f;
#pragma unroll
        for (int off = 32; off > 0; off >>= 1)
            v += __shfl_down(v, off, 64);
        if (lane == 0) loss[0] = v * (1.0f / (float)B);
    }
}

extern "C" void kernel_launch(void* const* d_in, const int* in_sizes, int n_in,
                              void* d_out, int out_size, void* d_ws, size_t ws_size,
                              hipStream_t stream) {
    const float4* out_p = (const float4*)d_in[0];
    const float4* lab_p = (const float4*)d_in[1];
    float* partials = (float*)d_ws;   // 4096 floats, fully overwritten

    sqdiff_partial_kernel<<<GRID, THREADS, 0, stream>>>(out_p, lab_p, partials);
    finalize_kernel<<<1, 1024, 0, stream>>>(partials, (float*)d_out);
}